// Round 2
// 844.549 us; speedup vs baseline: 1.0710x; 1.0710x over previous
//
#include <hip/hip_runtime.h>

#define BATCHN 131072
#define FD 512
#define F2 256
#define NOBJ 100000
#define NPRED 2000
#define LDSTR 520   // bf16 tile row stride (conflict-free b128 reads, verified in prior session)

typedef __bf16 bf16x8 __attribute__((ext_vector_type(8)));
typedef float f32x4 __attribute__((ext_vector_type(4)));

__device__ __forceinline__ ushort f2bf(float f) {
  union { float f; uint u; } c; c.f = f;
  uint u = c.u;
  u += 0x7FFFu + ((u >> 16) & 1u);   // RNE
  return (ushort)(u >> 16);
}

// ---------------- ws layout (float units) ----------------
// cnt (int): subj[100000], obj[100000], predi[2000] at 0 / 100000 / 200000
#define WS_STATS123 202752   // 3*1024: per-e [sum512, sumsq512]
#define WS_S4       205824   // 64 slots * [sum256, sumsq256]
#define WS_SCSH123  238592   // 3*1024
#define WS_SCSH4    241664   // 512
#define WS_W4BF     242176   // ushort[256*512] = 131072 ushorts = 65536 floats
#define WS_A1       307712   // 100000*256 f32   (FIX: was 274944, overlapped w4bf upper half)
#define WS_A2       25907712 // 100000*256 f32
#define WS_A3       51507712 // 2000*256 f32
// end: 52,019,712 floats = ~208.1 MB (requires ws_size >= 209 MB)

// ---------------- histogram of indices ----------------
__global__ __launch_bounds__(256) void k_hist(
    const int* __restrict__ subj, const int* __restrict__ obj,
    const int* __restrict__ predi, int* __restrict__ cnt)
{
  int b = blockIdx.x * 256 + threadIdx.x;
  atomicAdd(&cnt[subj[b]], 1);
  atomicAdd(&cnt[NOBJ + obj[b]], 1);
  atomicAdd(&cnt[2 * NOBJ + predi[b]], 1);
}

// ---------------- BN1/2/3 stats via weighted sequential scan ----------------
// sum_b W[idx_b][f] = sum_i cnt[i]*W[i][f]  (biases cancel in BN)
#define NB1 782   // ceil(100000/128)
#define NB3 16    // ceil(2000/128)
#define NB_SCAN (NB1 + NB1 + NB3)
__global__ __launch_bounds__(256) void k_scan123(
    const float* __restrict__ W1, const float* __restrict__ W2,
    const float* __restrict__ W3, const int* __restrict__ cnt,
    float* __restrict__ stats)
{
  int blk = blockIdx.x;
  int e, rowBase, N;
  if (blk < NB1)            { e = 0; rowBase = blk * 128;          N = NOBJ; }
  else if (blk < 2 * NB1)   { e = 1; rowBase = (blk - NB1) * 128;  N = NOBJ; }
  else                      { e = 2; rowBase = (blk - 2*NB1) * 128; N = NPRED; }
  const float* W = (e == 0) ? W1 : (e == 1 ? W2 : W3);
  const int* cn = cnt + (e == 0 ? 0 : (e == 1 ? NOBJ : 2 * NOBJ));

  __shared__ int cnL[128];
  __shared__ float redS[512], redQ[512];
  int t = threadIdx.x;
  if (t < 128) { int r = rowBase + t; cnL[t] = (r < N) ? cn[r] : 0; }
  redS[t] = 0.f; redS[t + 256] = 0.f; redQ[t] = 0.f; redQ[t + 256] = 0.f;
  __syncthreads();

  int c = t & 63, rg = t >> 6;   // lane c -> feats [8c, 8c+8); wave covers a 2KB row
  float s[8], q[8];
  #pragma unroll
  for (int j = 0; j < 8; ++j) { s[j] = 0.f; q[j] = 0.f; }
  for (int rl = rg; rl < 128; rl += 4) {
    float w = (float)cnL[rl];
    if (w == 0.f) continue;       // skip unused rows (incl. out-of-range)
    const float* row = W + (size_t)(rowBase + rl) * FD + c * 8;
    float4 va = *(const float4*)(row);
    float4 vb = *(const float4*)(row + 4);
    float x[8] = {va.x, va.y, va.z, va.w, vb.x, vb.y, vb.z, vb.w};
    #pragma unroll
    for (int j = 0; j < 8; ++j) { s[j] += w * x[j]; q[j] += w * x[j] * x[j]; }
  }
  #pragma unroll
  for (int j = 0; j < 8; ++j) {
    atomicAdd(&redS[c * 8 + j], s[j]);
    atomicAdd(&redQ[c * 8 + j], q[j]);
  }
  __syncthreads();
  float* se = stats + e * 1024;
  atomicAdd(&se[t],        redS[t]);
  atomicAdd(&se[t + 256],  redS[t + 256]);
  atomicAdd(&se[512 + t],  redQ[t]);
  atomicAdd(&se[768 + t],  redQ[t + 256]);
}

__global__ void k_fin123(const float* __restrict__ stats,
                         const float* __restrict__ g1, const float* __restrict__ be1,
                         const float* __restrict__ g2, const float* __restrict__ be2,
                         const float* __restrict__ g3, const float* __restrict__ be3,
                         float* __restrict__ scsh)
{
  int e = blockIdx.x, f = threadIdx.x;  // 3 x 512
  const float* g  = (e == 0) ? g1  : (e == 1 ? g2  : g3);
  const float* be = (e == 0) ? be1 : (e == 1 ? be2 : be3);
  float S = stats[e * 1024 + f], SS = stats[e * 1024 + 512 + f];
  const float invB = 1.f / (float)BATCHN;
  float mean = S * invB;
  float var  = SS * invB - mean * mean;
  if (!(var >= 0.f && var < 1e30f)) var = 1.f;
  if (!(mean > -1e30f && mean < 1e30f)) mean = 0.f;
  float r = rsqrtf(var + 1e-5f);
  float sc = g[f] * r;
  scsh[e * 1024 + f]       = sc;
  scsh[e * 1024 + 512 + f] = be[f] - mean * sc;
}

// ---------------- W4 fp32 -> bf16 ----------------
__global__ __launch_bounds__(256) void k_convW4(const float* __restrict__ W4,
                                                ushort* __restrict__ w4bf)
{
  int i = (blockIdx.x * 256 + threadIdx.x) * 4;
  float4 v = *(const float4*)(W4 + i);
  ushort4 o = {f2bf(v.x), f2bf(v.y), f2bf(v.z), f2bf(v.w)};
  *(ushort4*)(w4bf + i) = o;
}

// ---------------- A_e = relu(bn_e(W_e)) @ W4^T, per table row (once, not per batch elem) ----------------
#define NB_A1 3125  // 100000/32
#define NB_A3 63    // ceil(2000/32)
#define NB_BUILD (NB_A1 + NB_A1 + NB_A3)
__global__ __launch_bounds__(256) void k_buildA(
    const float* __restrict__ W1, const float* __restrict__ W2,
    const float* __restrict__ W3, const ushort* __restrict__ w4bf,
    const int* __restrict__ cnt, const float* __restrict__ scsh,
    float* __restrict__ A1, float* __restrict__ A2, float* __restrict__ A3)
{
  alignas(16) __shared__ ushort tileL[32 * LDSTR];  // 33,280 B; reused as f32 bounce [32*258]=33,024 B
  __shared__ int okL[32];
  int blk = blockIdx.x;
  int e, rowBase, N; const float* W; float* A; const int* cn;
  if (blk < NB_A1)          { e = 0; rowBase = blk * 32;             N = NOBJ;  W = W1; A = A1; cn = cnt; }
  else if (blk < 2 * NB_A1) { e = 1; rowBase = (blk - NB_A1) * 32;   N = NOBJ;  W = W2; A = A2; cn = cnt + NOBJ; }
  else                      { e = 2; rowBase = (blk - 2*NB_A1) * 32; N = NPRED; W = W3; A = A3; cn = cnt + 2 * NOBJ; }

  int t = threadIdx.x;
  if (t < 32) { int r = rowBase + t; okL[t] = (r < N) && (cn[r] != 0); }
  int c = t & 63, rg = t >> 6;
  float sc[8], sh[8];
  #pragma unroll
  for (int j = 0; j < 8; ++j) {
    sc[j] = scsh[e * 1024 + c * 8 + j];
    sh[j] = scsh[e * 1024 + 512 + c * 8 + j];
  }
  __syncthreads();

  // phase A: relu(sc*x+sh) rows -> LDS bf16
  for (int r = rg; r < 32; r += 4) {
    union { ushort o[8]; uint4 v; } u;
    if (okL[r]) {
      const float* row = W + (size_t)(rowBase + r) * FD + c * 8;
      float4 va = *(const float4*)(row);
      float4 vb = *(const float4*)(row + 4);
      float x[8] = {va.x, va.y, va.z, va.w, vb.x, vb.y, vb.z, vb.w};
      #pragma unroll
      for (int j = 0; j < 8; ++j) {
        float v = fmaxf(fmaf(sc[j], x[j], sh[j]), 0.f);
        v = fminf(v, 60000.f);
        u.o[j] = f2bf(v);
      }
    } else { u.v.x = 0; u.v.y = 0; u.v.z = 0; u.v.w = 0; }
    *(uint4*)&tileL[r * LDSTR + c * 8] = u.v;
  }
  __syncthreads();

  // phase B: 32x256x512 MFMA (layout identical to verified prior kernel)
  int w = t >> 6, lane = t & 63, m = lane & 15, q = lane >> 4;
  f32x4 acc[2][4];
  #pragma unroll
  for (int mi = 0; mi < 2; ++mi)
    #pragma unroll
    for (int ni = 0; ni < 4; ++ni)
      acc[mi][ni] = (f32x4){0.f, 0.f, 0.f, 0.f};
  const ushort* w4p = w4bf + ((size_t)(64 * w + m)) * FD + q * 8;
  const ushort* fpL = tileL + m * LDSTR + q * 8;
  for (int kk = 0; kk < 16; ++kk) {
    int kc = kk * 32;
    bf16x8 af0 = *(const bf16x8*)(fpL + kc);
    bf16x8 af1 = *(const bf16x8*)(fpL + 16 * LDSTR + kc);
    #pragma unroll
    for (int ni = 0; ni < 4; ++ni) {
      bf16x8 bfv = *(const bf16x8*)(w4p + ni * 16 * FD + kc);
      acc[0][ni] = __builtin_amdgcn_mfma_f32_16x16x32_bf16(af0, bfv, acc[0][ni], 0, 0, 0);
      acc[1][ni] = __builtin_amdgcn_mfma_f32_16x16x32_bf16(af1, bfv, acc[1][ni], 0, 0, 0);
    }
  }
  __syncthreads();  // done reading tileL as bf16

  // bounce acc -> LDS f32 (stride 258: max 2-way bank alias = free), then coalesced writeout
  float* ldsF = (float*)tileL;
  #pragma unroll
  for (int mi = 0; mi < 2; ++mi)
    #pragma unroll
    for (int ni = 0; ni < 4; ++ni)
      #pragma unroll
      for (int rr = 0; rr < 4; ++rr)
        ldsF[(16 * mi + 4 * q + rr) * 258 + 64 * w + 16 * ni + m] = acc[mi][ni][rr];
  __syncthreads();
  for (int r = 0; r < 32; ++r) {
    if (okL[r]) A[(size_t)(rowBase + r) * F2 + t] = ldsF[r * 258 + t];
  }
}

// ---------------- BN4 column stats of h = A1[s]+A2[o]+A3[p] (b4 cancels) ----------------
__global__ __launch_bounds__(256) void k_hstats(
    const int* __restrict__ subj, const int* __restrict__ obj,
    const int* __restrict__ predi,
    const float* __restrict__ A1, const float* __restrict__ A2,
    const float* __restrict__ A3, float* __restrict__ s4)
{
  __shared__ float colS[256], colQ[256];
  int t = threadIdx.x;
  colS[t] = 0.f; colQ[t] = 0.f;
  __syncthreads();
  int c = t & 31;       // 32 lanes cover one 1KB A row; lane c -> cols [8c, 8c+8)
  int pair = t >> 5;    // 8 half-waves, one sample each per iter
  float ls[8], lq[8];
  #pragma unroll
  for (int j = 0; j < 8; ++j) { ls[j] = 0.f; lq[j] = 0.f; }
  int base = blockIdx.x * 64;
  #pragma unroll 2
  for (int i = 0; i < 8; ++i) {
    int b = base + i * 8 + pair;
    const float* r1 = A1 + (size_t)subj[b]  * F2 + c * 8;
    const float* r2 = A2 + (size_t)obj[b]   * F2 + c * 8;
    const float* r3 = A3 + (size_t)predi[b] * F2 + c * 8;
    f32x4 a0 = *(const f32x4*)(r1), a1 = *(const f32x4*)(r1 + 4);
    f32x4 b0 = *(const f32x4*)(r2), b1 = *(const f32x4*)(r2 + 4);
    f32x4 c0 = *(const f32x4*)(r3), c1 = *(const f32x4*)(r3 + 4);
    f32x4 h0 = a0 + b0 + c0, h1 = a1 + b1 + c1;
    #pragma unroll
    for (int j = 0; j < 4; ++j) {
      ls[j]     += h0[j]; lq[j]     += h0[j] * h0[j];
      ls[4 + j] += h1[j]; lq[4 + j] += h1[j] * h1[j];
    }
  }
  #pragma unroll
  for (int j = 0; j < 8; ++j) {
    atomicAdd(&colS[c * 8 + j], ls[j]);
    atomicAdd(&colQ[c * 8 + j], lq[j]);
  }
  __syncthreads();
  int slot = blockIdx.x & 63;
  atomicAdd(&s4[slot * 512 + t],       colS[t]);
  atomicAdd(&s4[slot * 512 + 256 + t], colQ[t]);
}

__global__ void k_fin4(const float* __restrict__ s4, const float* __restrict__ g4,
                       const float* __restrict__ be4, float* __restrict__ scsh4)
{
  int j = threadIdx.x;  // 256
  float S = 0.f, SS = 0.f;
  for (int sl = 0; sl < 64; ++sl) { S += s4[sl * 512 + j]; SS += s4[sl * 512 + 256 + j]; }
  const float invB = 1.f / (float)BATCHN;
  float mean = S * invB;
  float var  = SS * invB - mean * mean;
  if (!(var >= 0.f && var < 1e30f)) var = 1.f;
  if (!(mean > -1e30f && mean < 1e30f)) mean = 0.f;
  float r = rsqrtf(var + 1e-5f);
  float sc = g4[j] * r;
  scsh4[j]       = sc;
  scsh4[256 + j] = be4[j] - mean * sc;
}

// ---------------- final: regather A rows, BN4+relu+dot(W5)+b5 -> logits ----------------
__global__ __launch_bounds__(256) void k_final(
    const int* __restrict__ subj, const int* __restrict__ obj,
    const int* __restrict__ predi,
    const float* __restrict__ A1, const float* __restrict__ A2,
    const float* __restrict__ A3, const float* __restrict__ scsh4,
    const float* __restrict__ W5, const float* __restrict__ b5,
    float* __restrict__ out)
{
  int t = threadIdx.x;
  int c = t & 31, pair = t >> 5;
  float sc4v[8], sh4v[8], w5v[8];
  #pragma unroll
  for (int j = 0; j < 8; ++j) {
    int col = c * 8 + j;
    sc4v[j] = scsh4[col];
    sh4v[j] = scsh4[256 + col];
    w5v[j]  = W5[col];
  }
  float bb = b5[0];
  int base = blockIdx.x * 64;
  #pragma unroll 2
  for (int i = 0; i < 8; ++i) {
    int b = base + i * 8 + pair;
    const float* r1 = A1 + (size_t)subj[b]  * F2 + c * 8;
    const float* r2 = A2 + (size_t)obj[b]   * F2 + c * 8;
    const float* r3 = A3 + (size_t)predi[b] * F2 + c * 8;
    f32x4 a0 = *(const f32x4*)(r1), a1 = *(const f32x4*)(r1 + 4);
    f32x4 b0 = *(const f32x4*)(r2), b1 = *(const f32x4*)(r2 + 4);
    f32x4 c0 = *(const f32x4*)(r3), c1 = *(const f32x4*)(r3 + 4);
    f32x4 h0 = a0 + b0 + c0, h1 = a1 + b1 + c1;
    float acc = 0.f;
    #pragma unroll
    for (int j = 0; j < 4; ++j) {
      acc += fmaxf(fmaf(sc4v[j],     h0[j], sh4v[j]),     0.f) * w5v[j];
      acc += fmaxf(fmaf(sc4v[4 + j], h1[j], sh4v[4 + j]), 0.f) * w5v[4 + j];
    }
    #pragma unroll
    for (int off = 1; off < 32; off <<= 1)
      acc += __shfl_xor(acc, off, 64);
    if (c == 0) out[b] = acc + bb;
  }
}

extern "C" void kernel_launch(void* const* d_in, const int* in_sizes, int n_in,
                              void* d_out, int out_size, void* d_ws, size_t ws_size,
                              hipStream_t stream)
{
  const int* subj  = (const int*)d_in[0];
  const int* obj   = (const int*)d_in[1];
  const int* predi = (const int*)d_in[2];
  const float* W1  = (const float*)d_in[3];
  // b1/b2/b3/b4 cancel inside their BatchNorms — never read
  const float* g1  = (const float*)d_in[5];
  const float* be1 = (const float*)d_in[6];
  const float* W2  = (const float*)d_in[7];
  const float* g2  = (const float*)d_in[9];
  const float* be2 = (const float*)d_in[10];
  const float* W3  = (const float*)d_in[11];
  const float* g3  = (const float*)d_in[13];
  const float* be3 = (const float*)d_in[14];
  const float* W4  = (const float*)d_in[15];
  const float* g4  = (const float*)d_in[17];
  const float* be4 = (const float*)d_in[18];
  const float* W5  = (const float*)d_in[19];
  const float* b5  = (const float*)d_in[20];

  float* wsf   = (float*)d_ws;
  int*   cnt   = (int*)d_ws;
  ushort* w4bf = (ushort*)(wsf + WS_W4BF);
  float* A1    = wsf + WS_A1;
  float* A2    = wsf + WS_A2;
  float* A3    = wsf + WS_A3;
  float* out   = (float*)d_out;

  hipMemsetAsync(d_ws, 0, WS_SCSH123 * 4, stream);  // zero cnt + stats123 + s4
  k_hist<<<BATCHN / 256, 256, 0, stream>>>(subj, obj, predi, cnt);
  k_convW4<<<128, 256, 0, stream>>>(W4, w4bf);
  k_scan123<<<NB_SCAN, 256, 0, stream>>>(W1, W2, W3, cnt, wsf + WS_STATS123);
  k_fin123<<<3, 512, 0, stream>>>(wsf + WS_STATS123, g1, be1, g2, be2, g3, be3, wsf + WS_SCSH123);
  k_buildA<<<NB_BUILD, 256, 0, stream>>>(W1, W2, W3, w4bf, cnt, wsf + WS_SCSH123, A1, A2, A3);
  k_hstats<<<BATCHN / 64, 256, 0, stream>>>(subj, obj, predi, A1, A2, A3, wsf + WS_S4);
  k_fin4<<<1, 256, 0, stream>>>(wsf + WS_S4, g4, be4, wsf + WS_SCSH4);
  k_final<<<BATCHN / 64, 256, 0, stream>>>(subj, obj, predi, A1, A2, A3, wsf + WS_SCSH4, W5, b5, out);
}

// Round 3
// 771.760 us; speedup vs baseline: 1.1720x; 1.0943x over previous
//
#include <hip/hip_runtime.h>

#define BATCHN 131072
#define FD 512
#define F2 256
#define NOBJ 100000
#define NPRED 2000
#define LDSTR 520   // bf16 tile row stride (conflict-free b128 reads, verified)

typedef __bf16 bf16x8 __attribute__((ext_vector_type(8)));
typedef float f32x4 __attribute__((ext_vector_type(4)));

__device__ __forceinline__ ushort f2bf(float f) {
  union { float f; uint u; } c; c.f = f;
  uint u = c.u;
  u += 0x7FFFu + ((u >> 16) & 1u);   // RNE
  return (ushort)(u >> 16);
}

// ---------------- ws layout (float units) ----------------
// cnt (int): subj[100000], obj[100000], predi[2000] at 0 / 100000 / 200000
#define WS_STATS123 202752   // 3*1024: per-e [sum512, sumsq512]
#define WS_S4       205824   // 64 slots * [sum256, sumsq256]
#define WS_SCSH123  238592   // 3*1024
#define WS_SCSH4    241664   // 512
#define WS_W4BF     242176   // ushort[256*512] = 65536 floats
#define WS_A1       307712   // bf16[100000*256] = 12.8M floats
#define WS_A2       13107712 // bf16[100000*256]
#define WS_A3       25907712 // bf16[2000*256] = 256000 floats
#define WS_H        26163712 // bf16[131072*256] = 16777216 floats
// end: 42,940,928 floats = ~172 MB (< 208 MB that previously passed)

// ---------------- histogram of indices ----------------
__global__ __launch_bounds__(256) void k_hist(
    const int* __restrict__ subj, const int* __restrict__ obj,
    const int* __restrict__ predi, int* __restrict__ cnt)
{
  int b = blockIdx.x * 256 + threadIdx.x;
  atomicAdd(&cnt[subj[b]], 1);
  atomicAdd(&cnt[NOBJ + obj[b]], 1);
  atomicAdd(&cnt[2 * NOBJ + predi[b]], 1);
}

// ---------------- BN1/2/3 stats via weighted sequential scan (compacted + 4-row ILP) ----------------
#define NB1 782   // ceil(100000/128)
#define NB3 16    // ceil(2000/128)
#define NB_SCAN (NB1 + NB1 + NB3)
__global__ __launch_bounds__(256) void k_scan123(
    const float* __restrict__ W1, const float* __restrict__ W2,
    const float* __restrict__ W3, const int* __restrict__ cnt,
    float* __restrict__ stats)
{
  int blk = blockIdx.x;
  int e, rowBase, N;
  if (blk < NB1)            { e = 0; rowBase = blk * 128;           N = NOBJ; }
  else if (blk < 2 * NB1)   { e = 1; rowBase = (blk - NB1) * 128;   N = NOBJ; }
  else                      { e = 2; rowBase = (blk - 2*NB1) * 128; N = NPRED; }
  const float* W = (e == 0) ? W1 : (e == 1 ? W2 : W3);
  const int* cn = cnt + (e == 0 ? 0 : (e == 1 ? NOBJ : 2 * NOBJ));

  __shared__ int cnL[128], listR[128], nkS;
  __shared__ float redS[512], redQ[512];
  int t = threadIdx.x;
  if (t == 0) nkS = 0;
  redS[t] = 0.f; redS[t + 256] = 0.f; redQ[t] = 0.f; redQ[t + 256] = 0.f;
  __syncthreads();
  if (t < 128) {
    int r = rowBase + t;
    int cv = (r < N) ? cn[r] : 0;
    cnL[t] = cv;
    if (cv > 0) { int p = atomicAdd(&nkS, 1); listR[p] = t; }
  }
  __syncthreads();
  int nk = nkS;

  int c = t & 63, rg = t >> 6;   // lane c -> feats [8c, 8c+8)
  float s[8], q[8];
  #pragma unroll
  for (int j = 0; j < 8; ++j) { s[j] = 0.f; q[j] = 0.f; }

  #define SCAN_ACC(w_, va_, vb_) { \
    float x_[8] = {va_.x, va_.y, va_.z, va_.w, vb_.x, vb_.y, vb_.z, vb_.w}; \
    _Pragma("unroll") \
    for (int j = 0; j < 8; ++j) { float wx = w_ * x_[j]; s[j] += wx; q[j] = fmaf(wx, x_[j], q[j]); } }

  int ii = rg;
  for (; ii + 12 < nk; ii += 16) {  // 4 rows per wave-iteration, 8 loads in flight
    int r0 = listR[ii], r1 = listR[ii + 4], r2 = listR[ii + 8], r3 = listR[ii + 12];
    const float* p0 = W + (size_t)(rowBase + r0) * FD + c * 8;
    const float* p1 = W + (size_t)(rowBase + r1) * FD + c * 8;
    const float* p2 = W + (size_t)(rowBase + r2) * FD + c * 8;
    const float* p3 = W + (size_t)(rowBase + r3) * FD + c * 8;
    float4 a0 = *(const float4*)(p0), b0 = *(const float4*)(p0 + 4);
    float4 a1 = *(const float4*)(p1), b1 = *(const float4*)(p1 + 4);
    float4 a2 = *(const float4*)(p2), b2 = *(const float4*)(p2 + 4);
    float4 a3 = *(const float4*)(p3), b3 = *(const float4*)(p3 + 4);
    float w0 = (float)cnL[r0], w1 = (float)cnL[r1], w2 = (float)cnL[r2], w3 = (float)cnL[r3];
    SCAN_ACC(w0, a0, b0); SCAN_ACC(w1, a1, b1); SCAN_ACC(w2, a2, b2); SCAN_ACC(w3, a3, b3);
  }
  for (; ii < nk; ii += 4) {
    int r0 = listR[ii];
    const float* p0 = W + (size_t)(rowBase + r0) * FD + c * 8;
    float4 a0 = *(const float4*)(p0), b0 = *(const float4*)(p0 + 4);
    float w0 = (float)cnL[r0];
    SCAN_ACC(w0, a0, b0);
  }
  #undef SCAN_ACC

  #pragma unroll
  for (int j = 0; j < 8; ++j) {
    atomicAdd(&redS[c * 8 + j], s[j]);
    atomicAdd(&redQ[c * 8 + j], q[j]);
  }
  __syncthreads();
  float* se = stats + e * 1024;
  atomicAdd(&se[t],        redS[t]);
  atomicAdd(&se[t + 256],  redS[t + 256]);
  atomicAdd(&se[512 + t],  redQ[t]);
  atomicAdd(&se[768 + t],  redQ[t + 256]);
}

__global__ void k_fin123(const float* __restrict__ stats,
                         const float* __restrict__ g1, const float* __restrict__ be1,
                         const float* __restrict__ g2, const float* __restrict__ be2,
                         const float* __restrict__ g3, const float* __restrict__ be3,
                         float* __restrict__ scsh)
{
  int e = blockIdx.x, f = threadIdx.x;  // 3 x 512
  const float* g  = (e == 0) ? g1  : (e == 1 ? g2  : g3);
  const float* be = (e == 0) ? be1 : (e == 1 ? be2 : be3);
  float S = stats[e * 1024 + f], SS = stats[e * 1024 + 512 + f];
  const float invB = 1.f / (float)BATCHN;
  float mean = S * invB;
  float var  = SS * invB - mean * mean;
  if (!(var >= 0.f && var < 1e30f)) var = 1.f;
  if (!(mean > -1e30f && mean < 1e30f)) mean = 0.f;
  float r = rsqrtf(var + 1e-5f);
  float sc = g[f] * r;
  scsh[e * 1024 + f]       = sc;
  scsh[e * 1024 + 512 + f] = be[f] - mean * sc;
}

// ---------------- W4 fp32 -> bf16 ----------------
__global__ __launch_bounds__(256) void k_convW4(const float* __restrict__ W4,
                                                ushort* __restrict__ w4bf)
{
  int i = (blockIdx.x * 256 + threadIdx.x) * 4;
  float4 v = *(const float4*)(W4 + i);
  ushort4 o = {f2bf(v.x), f2bf(v.y), f2bf(v.z), f2bf(v.w)};
  *(ushort4*)(w4bf + i) = o;
}

// ---------------- A_e = relu(bn_e(W_e)) @ W4^T per used table row; A stored bf16 ----------------
#define NB_A1 3125  // 100000/32
#define NB_A3 63    // ceil(2000/32)
#define NB_BUILD (NB_A1 + NB_A1 + NB_A3)
__global__ __launch_bounds__(256) void k_buildA(
    const float* __restrict__ W1, const float* __restrict__ W2,
    const float* __restrict__ W3, const ushort* __restrict__ w4bf,
    const int* __restrict__ cnt, const float* __restrict__ scsh,
    ushort* __restrict__ A1, ushort* __restrict__ A2, ushort* __restrict__ A3)
{
  alignas(16) __shared__ ushort tileL[32 * LDSTR];  // 33,280 B; reused as f32 bounce [32*258]
  __shared__ int okL[32], listR[32], nkS;
  int blk = blockIdx.x;
  int e, rowBase, N; const float* W; ushort* A; const int* cn;
  if (blk < NB_A1)          { e = 0; rowBase = blk * 32;             N = NOBJ;  W = W1; A = A1; cn = cnt; }
  else if (blk < 2 * NB_A1) { e = 1; rowBase = (blk - NB_A1) * 32;   N = NOBJ;  W = W2; A = A2; cn = cnt + NOBJ; }
  else                      { e = 2; rowBase = (blk - 2*NB_A1) * 32; N = NPRED; W = W3; A = A3; cn = cnt + 2 * NOBJ; }

  int t = threadIdx.x;
  if (t == 0) nkS = 0;
  __syncthreads();
  if (t < 32) {
    int r = rowBase + t;
    int ok = (r < N) && (cn[r] != 0);
    okL[t] = ok;
    if (ok) { int p = atomicAdd(&nkS, 1); listR[p] = t; }
  }
  int c = t & 63, rg = t >> 6;
  float sc[8], sh[8];
  #pragma unroll
  for (int j = 0; j < 8; ++j) {
    sc[j] = scsh[e * 1024 + c * 8 + j];
    sh[j] = scsh[e * 1024 + 512 + c * 8 + j];
  }
  __syncthreads();
  int nk = nkS;

  // phase A: relu(sc*x+sh) -> bf16 -> LDS, compacted rows, 2 rows (4 loads) in flight per wave
  #define CONV_STORE(rr_, va_, vb_) { \
    float x_[8] = {va_.x, va_.y, va_.z, va_.w, vb_.x, vb_.y, vb_.z, vb_.w}; \
    union { ushort o[8]; uint4 v; } u_; \
    _Pragma("unroll") \
    for (int j = 0; j < 8; ++j) { \
      float v_ = fmaxf(fmaf(sc[j], x_[j], sh[j]), 0.f); \
      v_ = fminf(v_, 60000.f); \
      u_.o[j] = f2bf(v_); } \
    *(uint4*)&tileL[(rr_) * LDSTR + c * 8] = u_.v; }

  int ii = rg;
  for (; ii + 4 < nk; ii += 8) {
    int ra = listR[ii], rb = listR[ii + 4];
    const float* pa = W + (size_t)(rowBase + ra) * FD + c * 8;
    const float* pb = W + (size_t)(rowBase + rb) * FD + c * 8;
    float4 a0 = *(const float4*)(pa), a1 = *(const float4*)(pa + 4);
    float4 b0 = *(const float4*)(pb), b1 = *(const float4*)(pb + 4);
    CONV_STORE(ra, a0, a1);
    CONV_STORE(rb, b0, b1);
  }
  if (ii < nk) {
    int ra = listR[ii];
    const float* pa = W + (size_t)(rowBase + ra) * FD + c * 8;
    float4 a0 = *(const float4*)(pa), a1 = *(const float4*)(pa + 4);
    CONV_STORE(ra, a0, a1);
  }
  #undef CONV_STORE
  __syncthreads();

  // phase B: 32x256x512 MFMA; B-frags software-pipelined (dead tile rows = garbage, never written out)
  int w = t >> 6, lane = t & 63, m = lane & 15, q = lane >> 4;
  f32x4 acc[2][4];
  #pragma unroll
  for (int mi = 0; mi < 2; ++mi)
    #pragma unroll
    for (int ni = 0; ni < 4; ++ni)
      acc[mi][ni] = (f32x4){0.f, 0.f, 0.f, 0.f};
  const ushort* w4p = w4bf + ((size_t)(64 * w + m)) * FD + q * 8;
  const ushort* fpL = tileL + m * LDSTR + q * 8;

  bf16x8 bc0 = *(const bf16x8*)(w4p + 0 * 16 * FD);
  bf16x8 bc1 = *(const bf16x8*)(w4p + 1 * 16 * FD);
  bf16x8 bc2 = *(const bf16x8*)(w4p + 2 * 16 * FD);
  bf16x8 bc3 = *(const bf16x8*)(w4p + 3 * 16 * FD);
  for (int kk = 0; kk < 16; ++kk) {
    int kc = kk * 32;
    bf16x8 af0 = *(const bf16x8*)(fpL + kc);
    bf16x8 af1 = *(const bf16x8*)(fpL + 16 * LDSTR + kc);
    bf16x8 bn0, bn1, bn2, bn3;
    if (kk < 15) {
      int kn = kc + 32;
      bn0 = *(const bf16x8*)(w4p + 0 * 16 * FD + kn);
      bn1 = *(const bf16x8*)(w4p + 1 * 16 * FD + kn);
      bn2 = *(const bf16x8*)(w4p + 2 * 16 * FD + kn);
      bn3 = *(const bf16x8*)(w4p + 3 * 16 * FD + kn);
    }
    acc[0][0] = __builtin_amdgcn_mfma_f32_16x16x32_bf16(af0, bc0, acc[0][0], 0, 0, 0);
    acc[1][0] = __builtin_amdgcn_mfma_f32_16x16x32_bf16(af1, bc0, acc[1][0], 0, 0, 0);
    acc[0][1] = __builtin_amdgcn_mfma_f32_16x16x32_bf16(af0, bc1, acc[0][1], 0, 0, 0);
    acc[1][1] = __builtin_amdgcn_mfma_f32_16x16x32_bf16(af1, bc1, acc[1][1], 0, 0, 0);
    acc[0][2] = __builtin_amdgcn_mfma_f32_16x16x32_bf16(af0, bc2, acc[0][2], 0, 0, 0);
    acc[1][2] = __builtin_amdgcn_mfma_f32_16x16x32_bf16(af1, bc2, acc[1][2], 0, 0, 0);
    acc[0][3] = __builtin_amdgcn_mfma_f32_16x16x32_bf16(af0, bc3, acc[0][3], 0, 0, 0);
    acc[1][3] = __builtin_amdgcn_mfma_f32_16x16x32_bf16(af1, bc3, acc[1][3], 0, 0, 0);
    bc0 = bn0; bc1 = bn1; bc2 = bn2; bc3 = bn3;
  }
  __syncthreads();  // done reading tileL as bf16

  // bounce acc -> LDS f32 (stride 258), then bf16 coalesced writeout of used rows
  float* ldsF = (float*)tileL;
  #pragma unroll
  for (int mi = 0; mi < 2; ++mi)
    #pragma unroll
    for (int ni = 0; ni < 4; ++ni)
      #pragma unroll
      for (int rr = 0; rr < 4; ++rr)
        ldsF[(16 * mi + 4 * q + rr) * 258 + 64 * w + 16 * ni + m] = acc[mi][ni][rr];
  __syncthreads();
  int hr = t >> 7, p = (t & 127) * 2;   // 2 rows per iteration; thread -> 2 floats -> 1 uint
  for (int r = 0; r < 32; r += 2) {
    int rr = r + hr;
    if (okL[rr]) {
      float v0 = ldsF[rr * 258 + p], v1 = ldsF[rr * 258 + p + 1];
      uint pack = (uint)f2bf(v0) | ((uint)f2bf(v1) << 16);
      *(uint*)&A[(size_t)(rowBase + rr) * F2 + p] = pack;
    }
  }
}

// ---------------- BN4 stats of h = A1[s]+A2[o]+A3[p]; also materialize h (bf16) ----------------
__global__ __launch_bounds__(256) void k_hstats(
    const int* __restrict__ subj, const int* __restrict__ obj,
    const int* __restrict__ predi,
    const ushort* __restrict__ A1, const ushort* __restrict__ A2,
    const ushort* __restrict__ A3, ushort* __restrict__ h,
    float* __restrict__ s4)
{
  __shared__ float colS[256], colQ[256];
  int t = threadIdx.x;
  colS[t] = 0.f; colQ[t] = 0.f;
  __syncthreads();
  int c = t & 31;       // lane c -> cols [8c, 8c+8); 32 lanes cover one 512B bf16 row
  int pair = t >> 5;    // 8 half-waves, one sample each per iter
  float ls[8], lq[8];
  #pragma unroll
  for (int j = 0; j < 8; ++j) { ls[j] = 0.f; lq[j] = 0.f; }
  int base = blockIdx.x * 64;
  #pragma unroll 2
  for (int i = 0; i < 8; ++i) {
    int b = base + i * 8 + pair;
    bf16x8 v1 = *(const bf16x8*)(A1 + (size_t)subj[b]  * F2 + c * 8);
    bf16x8 v2 = *(const bf16x8*)(A2 + (size_t)obj[b]   * F2 + c * 8);
    bf16x8 v3 = *(const bf16x8*)(A3 + (size_t)predi[b] * F2 + c * 8);
    union { ushort o[8]; uint4 v; } u;
    #pragma unroll
    for (int j = 0; j < 8; ++j) {
      float hv = (float)v1[j] + (float)v2[j] + (float)v3[j];
      ls[j] += hv; lq[j] = fmaf(hv, hv, lq[j]);
      u.o[j] = f2bf(hv);
    }
    *(uint4*)&h[(size_t)b * F2 + c * 8] = u.v;
  }
  #pragma unroll
  for (int j = 0; j < 8; ++j) {
    atomicAdd(&colS[c * 8 + j], ls[j]);
    atomicAdd(&colQ[c * 8 + j], lq[j]);
  }
  __syncthreads();
  int slot = blockIdx.x & 63;
  atomicAdd(&s4[slot * 512 + t],       colS[t]);
  atomicAdd(&s4[slot * 512 + 256 + t], colQ[t]);
}

__global__ void k_fin4(const float* __restrict__ s4, const float* __restrict__ g4,
                       const float* __restrict__ be4, float* __restrict__ scsh4)
{
  int j = threadIdx.x;  // 256
  float S = 0.f, SS = 0.f;
  for (int sl = 0; sl < 64; ++sl) { S += s4[sl * 512 + j]; SS += s4[sl * 512 + 256 + j]; }
  const float invB = 1.f / (float)BATCHN;
  float mean = S * invB;
  float var  = SS * invB - mean * mean;
  if (!(var >= 0.f && var < 1e30f)) var = 1.f;
  if (!(mean > -1e30f && mean < 1e30f)) mean = 0.f;
  float r = rsqrtf(var + 1e-5f);
  float sc = g4[j] * r;
  scsh4[j]       = sc;
  scsh4[256 + j] = be4[j] - mean * sc;
}

// ---------------- final: stream h (bf16), BN4+relu+dot(W5)+b5 -> logits ----------------
__global__ __launch_bounds__(256) void k_final(
    const ushort* __restrict__ h, const float* __restrict__ scsh4,
    const float* __restrict__ W5, const float* __restrict__ b5,
    float* __restrict__ out)
{
  int t = threadIdx.x;
  int c = t & 31, pair = t >> 5;
  float sc4v[8], sh4v[8], w5v[8];
  #pragma unroll
  for (int j = 0; j < 8; ++j) {
    int col = c * 8 + j;
    sc4v[j] = scsh4[col];
    sh4v[j] = scsh4[256 + col];
    w5v[j]  = W5[col];
  }
  float bb = b5[0];
  int base = blockIdx.x * 64;
  #pragma unroll 2
  for (int i = 0; i < 8; ++i) {
    int b = base + i * 8 + pair;
    bf16x8 hv = *(const bf16x8*)(h + (size_t)b * F2 + c * 8);
    float acc = 0.f;
    #pragma unroll
    for (int j = 0; j < 8; ++j)
      acc += fmaxf(fmaf(sc4v[j], (float)hv[j], sh4v[j]), 0.f) * w5v[j];
    #pragma unroll
    for (int off = 1; off < 32; off <<= 1)
      acc += __shfl_xor(acc, off, 64);
    if (c == 0) out[b] = acc + bb;
  }
}

extern "C" void kernel_launch(void* const* d_in, const int* in_sizes, int n_in,
                              void* d_out, int out_size, void* d_ws, size_t ws_size,
                              hipStream_t stream)
{
  const int* subj  = (const int*)d_in[0];
  const int* obj   = (const int*)d_in[1];
  const int* predi = (const int*)d_in[2];
  const float* W1  = (const float*)d_in[3];
  // b1/b2/b3/b4 cancel inside their BatchNorms — never read
  const float* g1  = (const float*)d_in[5];
  const float* be1 = (const float*)d_in[6];
  const float* W2  = (const float*)d_in[7];
  const float* g2  = (const float*)d_in[9];
  const float* be2 = (const float*)d_in[10];
  const float* W3  = (const float*)d_in[11];
  const float* g3  = (const float*)d_in[13];
  const float* be3 = (const float*)d_in[14];
  const float* W4  = (const float*)d_in[15];
  const float* g4  = (const float*)d_in[17];
  const float* be4 = (const float*)d_in[18];
  const float* W5  = (const float*)d_in[19];
  const float* b5  = (const float*)d_in[20];

  float* wsf   = (float*)d_ws;
  int*   cnt   = (int*)d_ws;
  ushort* w4bf = (ushort*)(wsf + WS_W4BF);
  ushort* A1   = (ushort*)(wsf + WS_A1);
  ushort* A2   = (ushort*)(wsf + WS_A2);
  ushort* A3   = (ushort*)(wsf + WS_A3);
  ushort* hbuf = (ushort*)(wsf + WS_H);
  float* out   = (float*)d_out;

  hipMemsetAsync(d_ws, 0, WS_SCSH123 * 4, stream);  // zero cnt + stats123 + s4
  k_hist<<<BATCHN / 256, 256, 0, stream>>>(subj, obj, predi, cnt);
  k_convW4<<<128, 256, 0, stream>>>(W4, w4bf);
  k_scan123<<<NB_SCAN, 256, 0, stream>>>(W1, W2, W3, cnt, wsf + WS_STATS123);
  k_fin123<<<3, 512, 0, stream>>>(wsf + WS_STATS123, g1, be1, g2, be2, g3, be3, wsf + WS_SCSH123);
  k_buildA<<<NB_BUILD, 256, 0, stream>>>(W1, W2, W3, w4bf, cnt, wsf + WS_SCSH123, A1, A2, A3);
  k_hstats<<<BATCHN / 64, 256, 0, stream>>>(subj, obj, predi, A1, A2, A3, hbuf, wsf + WS_S4);
  k_fin4<<<1, 256, 0, stream>>>(wsf + WS_S4, g4, be4, wsf + WS_SCSH4);
  k_final<<<BATCHN / 64, 256, 0, stream>>>(hbuf, wsf + WS_SCSH4, W5, b5, out);
}